// Round 6
// baseline (620.613 us; speedup 1.0000x reference)
//
#include <hip/hip_runtime.h>
#include <hip/hip_bf16.h>

#define BN 4
#define CC 256
#define C8 32
#define NN 4096
#define PROJ_ROWS 320
#define LOG2E 1.4426950408889634f

typedef __attribute__((ext_vector_type(8))) short short8;
typedef __attribute__((ext_vector_type(4))) float f32x4;

__device__ __forceinline__ unsigned short f2bf(float f) {
    unsigned u = __builtin_bit_cast(unsigned, f);
    unsigned r = (u + 0x7fffu + ((u >> 16) & 1u)) >> 16;
    return (unsigned short)r;
}
__device__ __forceinline__ float bfhi2f(unsigned u) {       // high 16 bits
    return __builtin_bit_cast(float, u & 0xffff0000u);
}
__device__ __forceinline__ float bflo2f(unsigned u) {       // low 16 bits
    return __builtin_bit_cast(float, u << 16);
}

// ---------------------------------------------------------------------------
// Projection GEMM. Block = (b, 32-wide n-tile), all 320 o-rows; x read once.
// Wk/bk pre-scaled by log2(e) so attn uses exp2 directly.
// Grid: 4*128 = 512 blocks, 256 threads.
// ---------------------------------------------------------------------------
__global__ __launch_bounds__(256) void proj_kernel(
    const float* __restrict__ x,
    const float* __restrict__ Wq, const float* __restrict__ bq,
    const float* __restrict__ Wk, const float* __restrict__ bk,
    const float* __restrict__ Wv, const float* __restrict__ bv,
    unsigned short* __restrict__ proj, unsigned short* __restrict__ qT)
{
    int bid = blockIdx.x;
    int b = bid >> 7, nt = bid & 127;
    int n0 = nt * 32;
    int tid = threadIdx.x;
    int w = tid >> 6, l = tid & 63, l15 = l & 15, lq = l >> 4;

    // Xt[n 32][c 256], stride 264 shorts = 528 B
    __shared__ alignas(16) unsigned short Xt[32][264];

    int c_l = tid >> 3;          // 0..31
    int nb  = (tid & 7) * 4;     // 0..28

#pragma unroll
    for (int kc = 0; kc < 8; kc++) {
        const float* xp = x + ((size_t)(b * CC + kc * 32 + c_l)) * NN + n0 + nb;
        float4 x0 = *(const float4*)xp;
        Xt[nb + 0][kc * 32 + c_l] = f2bf(x0.x);
        Xt[nb + 1][kc * 32 + c_l] = f2bf(x0.y);
        Xt[nb + 2][kc * 32 + c_l] = f2bf(x0.z);
        Xt[nb + 3][kc * 32 + c_l] = f2bf(x0.w);
    }
    __syncthreads();

    f32x4 acc[5][2];
#pragma unroll
    for (int gi = 0; gi < 5; gi++)
#pragma unroll
        for (int mi = 0; mi < 2; mi++) acc[gi][mi] = (f32x4){0.f, 0.f, 0.f, 0.f};

    for (int kc = 0; kc < 8; kc++) {
        float4 wf[5][2];
#pragma unroll
        for (int gi = 0; gi < 5; gi++) {
            int og = (w * 5 + gi) * 16 + l15;
            const float* wrow = (og < 32) ? (Wq + (size_t)og * CC)
                              : (og < 64) ? (Wk + (size_t)(og - 32) * CC)
                                          : (Wv + (size_t)(og - 64) * CC);
            const float* wp = wrow + kc * 32 + lq * 8;
            wf[gi][0] = *(const float4*)wp;
            wf[gi][1] = *(const float4*)(wp + 4);
        }
#pragma unroll
        for (int gi = 0; gi < 5; gi++) {
            unsigned short a8[8] __attribute__((aligned(16)));
            float tw[8] = {wf[gi][0].x, wf[gi][0].y, wf[gi][0].z, wf[gi][0].w,
                           wf[gi][1].x, wf[gi][1].y, wf[gi][1].z, wf[gi][1].w};
#pragma unroll
            for (int e = 0; e < 8; e++) a8[e] = f2bf(tw[e]);
            short8 af = *(const short8*)a8;
#pragma unroll
            for (int mi = 0; mi < 2; mi++) {
                short8 bf = *(const short8*)&Xt[mi * 16 + l15][kc * 32 + lq * 8];
                acc[gi][mi] = __builtin_amdgcn_mfma_f32_16x16x32_bf16(af, bf, acc[gi][mi], 0, 0, 0);
            }
        }
    }

    // epilogue: bias (+ log2e scaling for k rows) + bf16 store.
#pragma unroll
    for (int gi = 0; gi < 5; gi++) {
#pragma unroll
        for (int r = 0; r < 4; r++) {
            int og = (w * 5 + gi) * 16 + lq * 4 + r;
            float bias = (og < 32) ? bq[og] : (og < 64) ? bk[og - 32] : bv[og - 64];
            bool is_k = (og >= 32) && (og < 64);
#pragma unroll
            for (int mi = 0; mi < 2; mi++) {
                int n = n0 + mi * 16 + l15;
                float v = acc[gi][mi][r] + bias;
                if (is_k) v *= LOG2E;
                unsigned short v16 = f2bf(v);
                if (og < 32) {
                    qT[((size_t)b * NN + n) * C8 + og] = v16;
                } else {
                    proj[((size_t)b * PROJ_ROWS + og) * NN + n] = v16;
                }
            }
        }
    }
}

// ---------------------------------------------------------------------------
// Flash attention over the query axis (softmax over n), no max subtraction
// (shift-invariant; |S| bounded so exp2 is fp32-safe; k pre-scaled by log2e).
// R4 structure: 4 waves, ONE barrier per 64-n iteration, ps double-buffered:
//   barrier -> PV(ps[it&1]) -> S_{it+1} -> exp2 -> write ps[(it+1)&1].
// R6: NSPLIT=8 -> grid 2048 = 8 blocks/CU resident (LDS 19968*8 fits 160K;
// __launch_bounds__(256,8) pins VGPR<=64 = the 8-wave/SIMD boundary).
// Partial O stored as bf16 to keep combine traffic low.
// ---------------------------------------------------------------------------
template<int NSPLIT, bool FINAL>
__global__ __launch_bounds__(256, 8) void attn_kernel(
    const unsigned short* __restrict__ proj,
    const unsigned short* __restrict__ qT,
    const float* __restrict__ x,
    const float* __restrict__ gamma_p,
    float* __restrict__ out,
    unsigned short* __restrict__ Opart,
    float* __restrict__ Lpart)
{
    constexpr int ITERS = 64 / NSPLIT;
    int bid = blockIdx.x;
    int h   = bid >> 8;
    int low = bid & 255;
    int xcd = low & 7;   // HW round-robins consecutive blocks over 8 XCDs
    int b = xcd >> 1;
    int mtile = ((low >> 3) << 1) | (xcd & 1);
    int m0 = mtile * 64;
    int nbase = h * (ITERS * 64);

    int tid = threadIdx.x;
    int w = tid >> 6, l = tid & 63, l15 = l & 15, lq = l >> 4;

    __shared__ alignas(16) unsigned short ps[2][64][72];  // [buf][m][n]
    __shared__ float red[4][64];
    __shared__ float Ltot[64];

    const unsigned short* kbase = proj + ((size_t)b * PROJ_ROWS + C8) * NN;
    const unsigned short* vbase = proj + ((size_t)b * PROJ_ROWS + 64) * NN;
    const unsigned short* qbase = qT + (size_t)b * NN * C8;

    // k B-operand fragments (held all kernel): lane = k[c8=lq*8+j][m]
    short8 kfrag[4];
#pragma unroll
    for (int mi = 0; mi < 4; mi++) {
        int col = m0 + mi * 16 + l15;
        unsigned short t8[8] __attribute__((aligned(16)));
#pragma unroll
        for (int j = 0; j < 8; j++)
            t8[j] = kbase[(size_t)(lq * 8 + j) * NN + col];
        kfrag[mi] = *(const short8*)t8;
    }

    f32x4 O[4][4];
#pragma unroll
    for (int ci = 0; ci < 4; ci++)
#pragma unroll
        for (int mi = 0; mi < 4; mi++) O[ci][mi] = (f32x4){0.f, 0.f, 0.f, 0.f};
    float runS[4] = {0.f, 0.f, 0.f, 0.f};

    // prologue: S_0, exp2, write ps[0]
    {
        short8 qfrag = *(const short8*)(qbase + (size_t)(nbase + 16 * w + l15) * C8 + lq * 8);
#pragma unroll
        for (int mi = 0; mi < 4; mi++) {
            f32x4 S = __builtin_amdgcn_mfma_f32_16x16x32_bf16(
                qfrag, kfrag[mi], (f32x4){0.f, 0.f, 0.f, 0.f}, 0, 0, 0);
            float p0 = exp2f(S[0]);
            float p1 = exp2f(S[1]);
            float p2 = exp2f(S[2]);
            float p3 = exp2f(S[3]);
            runS[mi] += (p0 + p1) + (p2 + p3);
            unsigned pk0 = (unsigned)f2bf(p0) | ((unsigned)f2bf(p1) << 16);
            unsigned pk1 = (unsigned)f2bf(p2) | ((unsigned)f2bf(p3) << 16);
            *(uint2*)&ps[0][mi * 16 + l15][16 * w + lq * 4] = make_uint2(pk0, pk1);
        }
    }

    for (int it = 0; it < ITERS; it++) {
        int n0c = nbase + it * 64;
        __syncthreads();  // ps[it&1] visible; WAR on ps[(it+1)&1] cleared

        // PV: O[c,m] += V[c,n] . P[n,m]; wave w owns c in [64w,64w+64).
        const unsigned short* psrc = &ps[it & 1][0][0];
#pragma unroll
        for (int kh = 0; kh < 2; kh++) {
            short8 av[4];
#pragma unroll
            for (int ci = 0; ci < 4; ci++)
                av[ci] = *(const short8*)(vbase
                         + (size_t)(64 * w + ci * 16 + l15) * NN + n0c + kh * 32 + lq * 8);
            short8 bfr[4];
#pragma unroll
            for (int mi = 0; mi < 4; mi++)
                bfr[mi] = *(const short8*)(psrc + (mi * 16 + l15) * 72 + kh * 32 + lq * 8);
#pragma unroll
            for (int ci = 0; ci < 4; ci++)
#pragma unroll
                for (int mi = 0; mi < 4; mi++)
                    O[ci][mi] = __builtin_amdgcn_mfma_f32_16x16x32_bf16(
                        av[ci], bfr[mi], O[ci][mi], 0, 0, 0);
        }

        // S_{it+1}, exp2, write ps[(it+1)&1] — hidden until next barrier
        if (it + 1 < ITERS) {
            short8 qfrag = *(const short8*)(qbase
                           + (size_t)(n0c + 64 + 16 * w + l15) * C8 + lq * 8);
            unsigned short* pdst = &ps[(it + 1) & 1][0][0];
#pragma unroll
            for (int mi = 0; mi < 4; mi++) {
                f32x4 S = __builtin_amdgcn_mfma_f32_16x16x32_bf16(
                    qfrag, kfrag[mi], (f32x4){0.f, 0.f, 0.f, 0.f}, 0, 0, 0);
                float p0 = exp2f(S[0]);
                float p1 = exp2f(S[1]);
                float p2 = exp2f(S[2]);
                float p3 = exp2f(S[3]);
                runS[mi] += (p0 + p1) + (p2 + p3);
                unsigned pk0 = (unsigned)f2bf(p0) | ((unsigned)f2bf(p1) << 16);
                unsigned pk1 = (unsigned)f2bf(p2) | ((unsigned)f2bf(p3) << 16);
                *(uint2*)(pdst + (mi * 16 + l15) * 72 + 16 * w + lq * 4) = make_uint2(pk0, pk1);
            }
        }
    }

    // column-sum reduction: cross-lane (n row-groups), then cross-wave
#pragma unroll
    for (int mi = 0; mi < 4; mi++) {
        float s = runS[mi];
        s += __shfl_xor(s, 16);
        s += __shfl_xor(s, 32);
        red[w][mi * 16 + l15] = s;
    }
    __syncthreads();
    if (tid < 64) Ltot[tid] = red[0][tid] + red[1][tid] + red[2][tid] + red[3][tid];
    __syncthreads();

    if constexpr (FINAL) {
        float gamma = gamma_p[0];
        float iv[4];
#pragma unroll
        for (int mi = 0; mi < 4; mi++) iv[mi] = 1.0f / Ltot[mi * 16 + l15];
#pragma unroll
        for (int ci = 0; ci < 4; ci++) {
#pragma unroll
            for (int mi = 0; mi < 4; mi++) {
                int m = m0 + mi * 16 + l15;
#pragma unroll
                for (int r = 0; r < 4; r++) {
                    int c = 64 * w + ci * 16 + lq * 4 + r;
                    size_t idx = ((size_t)b * CC + c) * NN + m;
                    out[idx] = gamma * (O[ci][mi][r] * iv[mi]) + x[idx];
                }
            }
        }
    } else {
        size_t p = ((size_t)h * BN + b) * 64 + mtile;
        if (tid < 64) Lpart[p * 64 + tid] = Ltot[tid];
        unsigned short* Ob = Opart + p * (size_t)(CC * 64);
#pragma unroll
        for (int ci = 0; ci < 4; ci++) {
#pragma unroll
            for (int mi = 0; mi < 4; mi++) {
#pragma unroll
                for (int r = 0; r < 4; r++) {
                    int c = 64 * w + ci * 16 + lq * 4 + r;
                    Ob[c * 64 + mi * 16 + l15] = f2bf(O[ci][mi][r]);
                }
            }
        }
    }
}

// ---------------------------------------------------------------------------
// Combine: out = gamma * (sum_h O_h) / (sum_h L_h) + x. O partials are bf16.
// Grid 1024: one block per (b, mt, c-quarter).
// ---------------------------------------------------------------------------
template<int NSPLIT>
__global__ __launch_bounds__(256) void combine_kernel(
    const unsigned short* __restrict__ Opart, const float* __restrict__ Lpart,
    const float* __restrict__ x, const float* __restrict__ gamma_p,
    float* __restrict__ out)
{
    int bid = blockIdx.x;
    int cq = bid & 3;
    int mt = (bid >> 2) & 63;
    int b  = bid >> 8;
    int tid = threadIdx.x;
    int m4 = tid & 15, c16 = tid >> 4;
    float gamma = gamma_p[0];

    f32x4 Ls = (f32x4){0.f, 0.f, 0.f, 0.f};
#pragma unroll
    for (int h = 0; h < NSPLIT; h++) {
        size_t p = ((size_t)h * BN + b) * 64 + mt;
        Ls += *(const f32x4*)(Lpart + p * 64 + m4 * 4);
    }
    f32x4 inv;
#pragma unroll
    for (int j = 0; j < 4; j++) inv[j] = 1.0f / Ls[j];

#pragma unroll
    for (int cp = 0; cp < 4; cp++) {
        int c = cq * 64 + cp * 16 + c16;
        f32x4 acc = (f32x4){0.f, 0.f, 0.f, 0.f};
#pragma unroll
        for (int h = 0; h < NSPLIT; h++) {
            size_t p = ((size_t)h * BN + b) * 64 + mt;
            uint2 u = *(const uint2*)(Opart + p * (size_t)(CC * 64) + c * 64 + m4 * 4);
            acc[0] += bflo2f(u.x);
            acc[1] += bfhi2f(u.x);
            acc[2] += bflo2f(u.y);
            acc[3] += bfhi2f(u.y);
        }
        size_t idx = ((size_t)b * CC + c) * NN + mt * 64 + m4 * 4;
        f32x4 xv = *(const f32x4*)(x + idx);
        f32x4 o;
#pragma unroll
        for (int j = 0; j < 4; j++) o[j] = gamma * (acc[j] * inv[j]) + xv[j];
        *(f32x4*)(out + idx) = o;
    }
}

extern "C" void kernel_launch(void* const* d_in, const int* in_sizes, int n_in,
                              void* d_out, int out_size, void* d_ws, size_t ws_size,
                              hipStream_t stream) {
    const float* x     = (const float*)d_in[0];
    const float* Wq    = (const float*)d_in[1];
    const float* bq    = (const float*)d_in[2];
    const float* Wk    = (const float*)d_in[3];
    const float* bk    = (const float*)d_in[4];
    const float* Wv    = (const float*)d_in[5];
    const float* bv    = (const float*)d_in[6];
    const float* gamma = (const float*)d_in[7];
    float* out = (float*)d_out;
    (void)in_sizes; (void)n_in; (void)out_size;

    unsigned short* proj = (unsigned short*)d_ws;
    unsigned short* qT   = proj + (size_t)BN * PROJ_ROWS * NN;
    const size_t baseB = ((size_t)BN * PROJ_ROWS * NN + (size_t)BN * NN * C8) * 2;

    auto needB = [&](size_t ns) {
        size_t LpB = ns * BN * 64 * 64 * 4;                  // fp32 L partials
        size_t OpB = ns * BN * 64 * (size_t)(CC * 64) * 2;   // bf16 O partials
        return baseB + LpB + OpB;
    };

    proj_kernel<<<512, 256, 0, stream>>>(x, Wq, bq, Wk, bk, Wv, bv, proj, qT);

    if (ws_size >= needB(8)) {
        float* Lpart = (float*)((char*)d_ws + baseB);
        unsigned short* Opart = (unsigned short*)(Lpart + (size_t)8 * BN * 64 * 64);
        attn_kernel<8, false><<<2048, 256, 0, stream>>>(proj, qT, x, gamma, out, Opart, Lpart);
        combine_kernel<8><<<1024, 256, 0, stream>>>(Opart, Lpart, x, gamma, out);
    } else if (ws_size >= needB(4)) {
        float* Lpart = (float*)((char*)d_ws + baseB);
        unsigned short* Opart = (unsigned short*)(Lpart + (size_t)4 * BN * 64 * 64);
        attn_kernel<4, false><<<1024, 256, 0, stream>>>(proj, qT, x, gamma, out, Opart, Lpart);
        combine_kernel<4><<<1024, 256, 0, stream>>>(Opart, Lpart, x, gamma, out);
    } else {
        attn_kernel<1, true><<<256, 256, 0, stream>>>(proj, qT, x, gamma, out, nullptr, nullptr);
    }
}

// Round 7
// 188.533 us; speedup vs baseline: 3.2918x; 3.2918x over previous
//
#include <hip/hip_runtime.h>
#include <hip/hip_bf16.h>

#define BN 4
#define CC 256
#define C8 32
#define NN 4096
#define PROJ_ROWS 320
#define LOG2E 1.4426950408889634f

typedef __attribute__((ext_vector_type(8))) short short8;
typedef __attribute__((ext_vector_type(4))) float f32x4;

__device__ __forceinline__ unsigned short f2bf(float f) {
    unsigned u = __builtin_bit_cast(unsigned, f);
    unsigned r = (u + 0x7fffu + ((u >> 16) & 1u)) >> 16;
    return (unsigned short)r;
}
__device__ __forceinline__ float bfhi2f(unsigned u) { return __builtin_bit_cast(float, u & 0xffff0000u); }
__device__ __forceinline__ float bflo2f(unsigned u) { return __builtin_bit_cast(float, u << 16); }

// ---------------------------------------------------------------------------
// Projection GEMM (R6, known-good). Block = (b, 32-n tile), all 320 o-rows.
// Wk/bk pre-scaled by log2(e). Grid 512, 256 threads.
// ---------------------------------------------------------------------------
__global__ __launch_bounds__(256) void proj_kernel(
    const float* __restrict__ x,
    const float* __restrict__ Wq, const float* __restrict__ bq,
    const float* __restrict__ Wk, const float* __restrict__ bk,
    const float* __restrict__ Wv, const float* __restrict__ bv,
    unsigned short* __restrict__ proj, unsigned short* __restrict__ qT)
{
    int bid = blockIdx.x;
    int b = bid >> 7, nt = bid & 127;
    int n0 = nt * 32;
    int tid = threadIdx.x;
    int w = tid >> 6, l = tid & 63, l15 = l & 15, lq = l >> 4;

    __shared__ alignas(16) unsigned short Xt[32][264];

    int c_l = tid >> 3;
    int nb  = (tid & 7) * 4;

#pragma unroll
    for (int kc = 0; kc < 8; kc++) {
        const float* xp = x + ((size_t)(b * CC + kc * 32 + c_l)) * NN + n0 + nb;
        float4 x0 = *(const float4*)xp;
        Xt[nb + 0][kc * 32 + c_l] = f2bf(x0.x);
        Xt[nb + 1][kc * 32 + c_l] = f2bf(x0.y);
        Xt[nb + 2][kc * 32 + c_l] = f2bf(x0.z);
        Xt[nb + 3][kc * 32 + c_l] = f2bf(x0.w);
    }
    __syncthreads();

    f32x4 acc[5][2];
#pragma unroll
    for (int gi = 0; gi < 5; gi++)
#pragma unroll
        for (int mi = 0; mi < 2; mi++) acc[gi][mi] = (f32x4){0.f, 0.f, 0.f, 0.f};

    for (int kc = 0; kc < 8; kc++) {
        float4 wf[5][2];
#pragma unroll
        for (int gi = 0; gi < 5; gi++) {
            int og = (w * 5 + gi) * 16 + l15;
            const float* wrow = (og < 32) ? (Wq + (size_t)og * CC)
                              : (og < 64) ? (Wk + (size_t)(og - 32) * CC)
                                          : (Wv + (size_t)(og - 64) * CC);
            const float* wp = wrow + kc * 32 + lq * 8;
            wf[gi][0] = *(const float4*)wp;
            wf[gi][1] = *(const float4*)(wp + 4);
        }
#pragma unroll
        for (int gi = 0; gi < 5; gi++) {
            unsigned short a8[8] __attribute__((aligned(16)));
            float tw[8] = {wf[gi][0].x, wf[gi][0].y, wf[gi][0].z, wf[gi][0].w,
                           wf[gi][1].x, wf[gi][1].y, wf[gi][1].z, wf[gi][1].w};
#pragma unroll
            for (int e = 0; e < 8; e++) a8[e] = f2bf(tw[e]);
            short8 af = *(const short8*)a8;
#pragma unroll
            for (int mi = 0; mi < 2; mi++) {
                short8 bf = *(const short8*)&Xt[mi * 16 + l15][kc * 32 + lq * 8];
                acc[gi][mi] = __builtin_amdgcn_mfma_f32_16x16x32_bf16(af, bf, acc[gi][mi], 0, 0, 0);
            }
        }
    }

#pragma unroll
    for (int gi = 0; gi < 5; gi++) {
#pragma unroll
        for (int r = 0; r < 4; r++) {
            int og = (w * 5 + gi) * 16 + lq * 4 + r;
            float bias = (og < 32) ? bq[og] : (og < 64) ? bk[og - 32] : bv[og - 64];
            bool is_k = (og >= 32) && (og < 64);
#pragma unroll
            for (int mi = 0; mi < 2; mi++) {
                int n = n0 + mi * 16 + l15;
                float v = acc[gi][mi][r] + bias;
                if (is_k) v *= LOG2E;
                unsigned short v16 = f2bf(v);
                if (og < 32) {
                    qT[((size_t)b * NN + n) * C8 + og] = v16;
                } else {
                    proj[((size_t)b * PROJ_ROWS + og) * NN + n] = v16;
                }
            }
        }
    }
}

// ---------------------------------------------------------------------------
// Flash attention over the query axis (softmax over n, shift-invariant so no
// max subtraction; k pre-scaled by log2e -> exp2). 4 waves, block covers
// 128 c (ch half) x 64 m; each wave 32c x 64m -> O = 32 VGPRs. ps double-
// buffered, ONE barrier/iter. av register-prefetched one iteration ahead,
// issued a full phase before the barrier that drains it.
// ---------------------------------------------------------------------------
template<int NSPLIT, bool FINAL>
__global__ __launch_bounds__(256, 4) void attn_kernel(
    const unsigned short* __restrict__ proj,
    const unsigned short* __restrict__ qT,
    const float* __restrict__ x,
    const float* __restrict__ gamma_p,
    float* __restrict__ out,
    unsigned short* __restrict__ Opart,
    float* __restrict__ Lpart)
{
    constexpr int ITERS = 64 / NSPLIT;
    int bid = blockIdx.x;
    int low = bid & 255;
    int xcd = low & 7;
    int b = xcd >> 1;
    int mtile = ((low >> 3) << 1) | (xcd & 1);
    int m0 = mtile * 64;
    int ch = (bid >> 8) & 1;
    int h  = bid >> 9;
    int nbase = h * (ITERS * 64);

    int tid = threadIdx.x;
    int w = tid >> 6, l = tid & 63, l15 = l & 15, lq = l >> 4;
    int cw = ch * 128 + w * 32;   // this wave's c base (32 c rows)

    __shared__ alignas(16) unsigned short ps[2][64][72];  // [buf][m][n]
    __shared__ float red[4][64];
    __shared__ float Ltot[64];

    const unsigned short* kbase = proj + ((size_t)b * PROJ_ROWS + C8) * NN;
    const unsigned short* vbase = proj + ((size_t)b * PROJ_ROWS + 64) * NN;
    const unsigned short* qbase = qT + (size_t)b * NN * C8;

    // k B-operand fragments: lane = k[c8=lq*8+j][m = m0+mi*16+l15]
    short8 kfrag[4];
#pragma unroll
    for (int mi = 0; mi < 4; mi++) {
        int col = m0 + mi * 16 + l15;
        unsigned short t8[8] __attribute__((aligned(16)));
#pragma unroll
        for (int j = 0; j < 8; j++)
            t8[j] = kbase[(size_t)(lq * 8 + j) * NN + col];
        kfrag[mi] = *(const short8*)t8;
    }

    f32x4 O[2][4];
#pragma unroll
    for (int ci = 0; ci < 2; ci++)
#pragma unroll
        for (int mi = 0; mi < 4; mi++) O[ci][mi] = (f32x4){0.f, 0.f, 0.f, 0.f};
    float runS[4] = {0.f, 0.f, 0.f, 0.f};

    // prologue: prefetch av for iter 0; S_0 -> exp2 -> ps[0]
    short8 avc[2][2];   // [kh][ci]: A-operand V[c=cw+ci*16+l15][n=kh*32+lq*8..+8]
#pragma unroll
    for (int kh = 0; kh < 2; kh++)
#pragma unroll
        for (int ci = 0; ci < 2; ci++)
            avc[kh][ci] = *(const short8*)(vbase
                + (size_t)(cw + ci * 16 + l15) * NN + nbase + kh * 32 + lq * 8);
    {
        short8 qf = *(const short8*)(qbase + (size_t)(nbase + 16 * w + l15) * C8 + lq * 8);
#pragma unroll
        for (int mi = 0; mi < 4; mi++) {
            f32x4 S = __builtin_amdgcn_mfma_f32_16x16x32_bf16(
                qf, kfrag[mi], (f32x4){0.f, 0.f, 0.f, 0.f}, 0, 0, 0);
            float p0 = exp2f(S[0]), p1 = exp2f(S[1]), p2 = exp2f(S[2]), p3 = exp2f(S[3]);
            runS[mi] += (p0 + p1) + (p2 + p3);
            unsigned pk0 = (unsigned)f2bf(p0) | ((unsigned)f2bf(p1) << 16);
            unsigned pk1 = (unsigned)f2bf(p2) | ((unsigned)f2bf(p3) << 16);
            *(uint2*)&ps[0][mi * 16 + l15][16 * w + lq * 4] = make_uint2(pk0, pk1);
        }
    }

    for (int it = 0; it < ITERS; it++) {
        int n0c = nbase + it * 64;
        __syncthreads();  // ps[it&1] visible; WAR on ps[(it+1)&1] cleared

        // prefetch operands for it+1 NOW (consumed next iter; the barrier
        // that drains them is a full phase away -> latency fully hidden)
        short8 avn[2][2];
        short8 qn;
        if (it + 1 < ITERS) {
            int nn = n0c + 64;
#pragma unroll
            for (int kh = 0; kh < 2; kh++)
#pragma unroll
                for (int ci = 0; ci < 2; ci++)
                    avn[kh][ci] = *(const short8*)(vbase
                        + (size_t)(cw + ci * 16 + l15) * NN + nn + kh * 32 + lq * 8);
            qn = *(const short8*)(qbase + (size_t)(nn + 16 * w + l15) * C8 + lq * 8);
        }

        // PV: O[c,m] += V[c,n] . P[n,m]
        const unsigned short* psrc = &ps[it & 1][0][0];
#pragma unroll
        for (int kh = 0; kh < 2; kh++) {
            short8 bfr[4];
#pragma unroll
            for (int mi = 0; mi < 4; mi++)
                bfr[mi] = *(const short8*)(psrc + (mi * 16 + l15) * 72 + kh * 32 + lq * 8);
#pragma unroll
            for (int ci = 0; ci < 2; ci++)
#pragma unroll
                for (int mi = 0; mi < 4; mi++)
                    O[ci][mi] = __builtin_amdgcn_mfma_f32_16x16x32_bf16(
                        avc[kh][ci], bfr[mi], O[ci][mi], 0, 0, 0);
        }

        // S_{it+1} -> exp2 -> write ps[(it+1)&1]
        if (it + 1 < ITERS) {
#pragma unroll
            for (int mi = 0; mi < 4; mi++) {
                f32x4 S = __builtin_amdgcn_mfma_f32_16x16x32_bf16(
                    qn, kfrag[mi], (f32x4){0.f, 0.f, 0.f, 0.f}, 0, 0, 0);
                float p0 = exp2f(S[0]), p1 = exp2f(S[1]), p2 = exp2f(S[2]), p3 = exp2f(S[3]);
                runS[mi] += (p0 + p1) + (p2 + p3);
                unsigned pk0 = (unsigned)f2bf(p0) | ((unsigned)f2bf(p1) << 16);
                unsigned pk1 = (unsigned)f2bf(p2) | ((unsigned)f2bf(p3) << 16);
                *(uint2*)(&ps[(it + 1) & 1][0][0] + (mi * 16 + l15) * 72 + 16 * w + lq * 4)
                    = make_uint2(pk0, pk1);
            }
#pragma unroll
            for (int kh = 0; kh < 2; kh++)
#pragma unroll
                for (int ci = 0; ci < 2; ci++) avc[kh][ci] = avn[kh][ci];
        }
    }

    // column sums: cross-lane (row quads), then cross-wave via LDS
#pragma unroll
    for (int mi = 0; mi < 4; mi++) {
        float s = runS[mi];
        s += __shfl_xor(s, 16);
        s += __shfl_xor(s, 32);
        red[w][mi * 16 + l15] = s;
    }
    __syncthreads();
    if (tid < 64) Ltot[tid] = red[0][tid] + red[1][tid] + red[2][tid] + red[3][tid];
    __syncthreads();

    if constexpr (FINAL) {
        float gamma = gamma_p[0];
        float iv[4];
#pragma unroll
        for (int mi = 0; mi < 4; mi++) iv[mi] = 1.0f / Ltot[mi * 16 + l15];
#pragma unroll
        for (int ci = 0; ci < 2; ci++) {
#pragma unroll
            for (int mi = 0; mi < 4; mi++) {
                int m = m0 + mi * 16 + l15;
#pragma unroll
                for (int r = 0; r < 4; r++) {
                    int c = cw + ci * 16 + lq * 4 + r;
                    size_t idx = ((size_t)b * CC + c) * NN + m;
                    out[idx] = gamma * (O[ci][mi][r] * iv[mi]) + x[idx];
                }
            }
        }
    } else {
        size_t p = ((size_t)h * BN + b) * 64 + mtile;
        if (ch == 0 && tid < 64) Lpart[p * 64 + tid] = Ltot[tid];
        // Opart layout [p][m 64][c 256] bf16; r is c-contiguous -> uint2 stores
        unsigned short* Ob = Opart + p * (size_t)(64 * 256);
#pragma unroll
        for (int ci = 0; ci < 2; ci++) {
#pragma unroll
            for (int mi = 0; mi < 4; mi++) {
                unsigned pk0 = (unsigned)f2bf(O[ci][mi][0]) | ((unsigned)f2bf(O[ci][mi][1]) << 16);
                unsigned pk1 = (unsigned)f2bf(O[ci][mi][2]) | ((unsigned)f2bf(O[ci][mi][3]) << 16);
                *(uint2*)(Ob + (size_t)(mi * 16 + l15) * 256 + cw + ci * 16 + lq * 4)
                    = make_uint2(pk0, pk1);
            }
        }
    }
}

// ---------------------------------------------------------------------------
// Combine: out = gamma * (sum_h O_h) / (sum_h L_h) + x. Opart bf16 [m][c].
// LDS transpose for coalesced out writes. Grid 256 = (b, mt).
// ---------------------------------------------------------------------------
template<int NSPLIT>
__global__ __launch_bounds__(256) void combine_kernel(
    const unsigned short* __restrict__ Opart, const float* __restrict__ Lpart,
    const float* __restrict__ x, const float* __restrict__ gamma_p,
    float* __restrict__ out)
{
    int bid = blockIdx.x;
    int b = bid >> 6, mt = bid & 63;
    int tid = threadIdx.x;
    float gamma = gamma_p[0];

    __shared__ float trans[64][65];   // [c][m], stride 65 -> 2-way banks max

    int m  = tid >> 2;                // phase A: one m per thread
    int cg = (tid & 3) * 16;          // 16-c group

    float Ls = 0.f;
#pragma unroll
    for (int hh = 0; hh < NSPLIT; hh++)
        Ls += Lpart[(((size_t)hh * BN + b) * 64 + mt) * 64 + m];
    float scale = gamma / Ls;

    for (int cc = 0; cc < 4; cc++) {
        float acc[16];
#pragma unroll
        for (int j = 0; j < 16; j++) acc[j] = 0.f;
#pragma unroll
        for (int hh = 0; hh < NSPLIT; hh++) {
            const unsigned short* row = Opart
                + (((size_t)hh * BN + b) * 64 + mt) * (size_t)(64 * 256)
                + (size_t)m * 256 + cc * 64 + cg;
#pragma unroll
            for (int j4 = 0; j4 < 4; j4++) {
                uint2 u = *(const uint2*)(row + j4 * 4);
                acc[j4 * 4 + 0] += bflo2f(u.x);
                acc[j4 * 4 + 1] += bfhi2f(u.x);
                acc[j4 * 4 + 2] += bflo2f(u.y);
                acc[j4 * 4 + 3] += bfhi2f(u.y);
            }
        }
        if (cc) __syncthreads();
#pragma unroll
        for (int j = 0; j < 16; j++) trans[cg + j][m] = acc[j] * scale;
        __syncthreads();

        // phase B: c = tid>>2 (within chunk), 16 m per thread, coalesced out
        int c  = tid >> 2;
        int mg = (tid & 3) * 16;
        size_t idx = ((size_t)b * CC + cc * 64 + c) * NN + mt * 64 + mg;
#pragma unroll
        for (int j4 = 0; j4 < 4; j4++) {
            f32x4 xv = *(const f32x4*)(x + idx + j4 * 4);
            f32x4 o;
#pragma unroll
            for (int j = 0; j < 4; j++) o[j] = trans[c][mg + j4 * 4 + j] + xv[j];
            *(f32x4*)(out + idx + j4 * 4) = o;
        }
    }
}

extern "C" void kernel_launch(void* const* d_in, const int* in_sizes, int n_in,
                              void* d_out, int out_size, void* d_ws, size_t ws_size,
                              hipStream_t stream) {
    const float* x     = (const float*)d_in[0];
    const float* Wq    = (const float*)d_in[1];
    const float* bq    = (const float*)d_in[2];
    const float* Wk    = (const float*)d_in[3];
    const float* bk    = (const float*)d_in[4];
    const float* Wv    = (const float*)d_in[5];
    const float* bv    = (const float*)d_in[6];
    const float* gamma = (const float*)d_in[7];
    float* out = (float*)d_out;
    (void)in_sizes; (void)n_in; (void)out_size;

    unsigned short* proj = (unsigned short*)d_ws;
    unsigned short* qT   = proj + (size_t)BN * PROJ_ROWS * NN;
    const size_t baseB = ((size_t)BN * PROJ_ROWS * NN + (size_t)BN * NN * C8) * 2;

    auto needB = [&](size_t ns) {
        size_t LpB = ns * BN * 64 * 64 * 4;                  // fp32 L partials
        size_t OpB = ns * BN * 64 * (size_t)(64 * 256) * 2;  // bf16 O partials
        return baseB + LpB + OpB;
    };

    proj_kernel<<<512, 256, 0, stream>>>(x, Wq, bq, Wk, bk, Wv, bv, proj, qT);

    if (ws_size >= needB(4)) {
        float* Lpart = (float*)((char*)d_ws + baseB);
        unsigned short* Opart = (unsigned short*)(Lpart + (size_t)4 * BN * 64 * 64);
        attn_kernel<4, false><<<2048, 256, 0, stream>>>(proj, qT, x, gamma, out, Opart, Lpart);
        combine_kernel<4><<<256, 256, 0, stream>>>(Opart, Lpart, x, gamma, out);
    } else if (ws_size >= needB(2)) {
        float* Lpart = (float*)((char*)d_ws + baseB);
        unsigned short* Opart = (unsigned short*)(Lpart + (size_t)2 * BN * 64 * 64);
        attn_kernel<2, false><<<1024, 256, 0, stream>>>(proj, qT, x, gamma, out, Opart, Lpart);
        combine_kernel<2><<<256, 256, 0, stream>>>(Opart, Lpart, x, gamma, out);
    } else {
        attn_kernel<1, true><<<512, 256, 0, stream>>>(proj, qT, x, gamma, out, nullptr, nullptr);
    }
}

// Round 8
// 183.297 us; speedup vs baseline: 3.3858x; 1.0286x over previous
//
#include <hip/hip_runtime.h>
#include <hip/hip_bf16.h>

#define BN 4
#define CC 256
#define C8 32
#define NN 4096
#define PROJ_ROWS 320
#define LOG2E 1.4426950408889634f

typedef __attribute__((ext_vector_type(8))) short short8;
typedef __attribute__((ext_vector_type(4))) float f32x4;

__device__ __forceinline__ unsigned short f2bf(float f) {
    unsigned u = __builtin_bit_cast(unsigned, f);
    unsigned r = (u + 0x7fffu + ((u >> 16) & 1u)) >> 16;
    return (unsigned short)r;
}
// pack two fp32 -> two bf16 in one dword (v_cvt_pk_bf16_f32 on gfx950)
__device__ __forceinline__ unsigned pk2bf(float a, float b) {
#if __has_builtin(__builtin_amdgcn_cvt_pk_bf16_f32)
    auto v = __builtin_amdgcn_cvt_pk_bf16_f32(a, b);
    return __builtin_bit_cast(unsigned, v);
#else
    return (unsigned)f2bf(a) | ((unsigned)f2bf(b) << 16);
#endif
}
__device__ __forceinline__ float bfhi2f(unsigned u) { return __builtin_bit_cast(float, u & 0xffff0000u); }
__device__ __forceinline__ float bflo2f(unsigned u) { return __builtin_bit_cast(float, u << 16); }

// ---------------------------------------------------------------------------
// W pre-cast: Wbf[o 320][c 256] bf16, k-rows (32..63) pre-scaled by log2(e).
// Grid 320 blocks x 256 threads.
// ---------------------------------------------------------------------------
__global__ __launch_bounds__(256) void wcast_kernel(
    const float* __restrict__ Wq, const float* __restrict__ Wk,
    const float* __restrict__ Wv, unsigned short* __restrict__ Wbf)
{
    int o = blockIdx.x, c = threadIdx.x;
    float v;
    if (o < 32)      v = Wq[(size_t)o * CC + c];
    else if (o < 64) v = Wk[(size_t)(o - 32) * CC + c] * LOG2E;
    else             v = Wv[(size_t)(o - 64) * CC + c];
    Wbf[(size_t)o * CC + c] = f2bf(v);
}

// ---------------------------------------------------------------------------
// Projection GEMM. Block = (b, 32-n tile), all 320 o-rows; x read once.
// W A-fragments are direct 16B bf16 loads from Wbf (L2-hot).
// Grid 512, 256 threads.
// ---------------------------------------------------------------------------
__global__ __launch_bounds__(256) void proj_kernel(
    const float* __restrict__ x,
    const unsigned short* __restrict__ Wbf,
    const float* __restrict__ bq, const float* __restrict__ bk,
    const float* __restrict__ bv,
    unsigned short* __restrict__ proj, unsigned short* __restrict__ qT)
{
    int bid = blockIdx.x;
    int b = bid >> 7, nt = bid & 127;
    int n0 = nt * 32;
    int tid = threadIdx.x;
    int w = tid >> 6, l = tid & 63, l15 = l & 15, lq = l >> 4;

    __shared__ alignas(16) unsigned short Xt[32][264];

    int c_l = tid >> 3;
    int nb  = (tid & 7) * 4;

#pragma unroll
    for (int kc = 0; kc < 8; kc++) {
        const float* xp = x + ((size_t)(b * CC + kc * 32 + c_l)) * NN + n0 + nb;
        float4 x0 = *(const float4*)xp;
        Xt[nb + 0][kc * 32 + c_l] = f2bf(x0.x);
        Xt[nb + 1][kc * 32 + c_l] = f2bf(x0.y);
        Xt[nb + 2][kc * 32 + c_l] = f2bf(x0.z);
        Xt[nb + 3][kc * 32 + c_l] = f2bf(x0.w);
    }
    __syncthreads();

    f32x4 acc[5][2];
#pragma unroll
    for (int gi = 0; gi < 5; gi++)
#pragma unroll
        for (int mi = 0; mi < 2; mi++) acc[gi][mi] = (f32x4){0.f, 0.f, 0.f, 0.f};

    for (int kc = 0; kc < 8; kc++) {
        short8 af[5];
#pragma unroll
        for (int gi = 0; gi < 5; gi++) {
            int og = (w * 5 + gi) * 16 + l15;
            af[gi] = *(const short8*)(Wbf + (size_t)og * CC + kc * 32 + lq * 8);
        }
#pragma unroll
        for (int gi = 0; gi < 5; gi++) {
#pragma unroll
            for (int mi = 0; mi < 2; mi++) {
                short8 bf = *(const short8*)&Xt[mi * 16 + l15][kc * 32 + lq * 8];
                acc[gi][mi] = __builtin_amdgcn_mfma_f32_16x16x32_bf16(af[gi], bf, acc[gi][mi], 0, 0, 0);
            }
        }
    }

    // epilogue: bias (bk pre-scaled by log2e to match W scaling) + bf16 store
#pragma unroll
    for (int gi = 0; gi < 5; gi++) {
#pragma unroll
        for (int r = 0; r < 4; r++) {
            int og = (w * 5 + gi) * 16 + lq * 4 + r;
            float bias = (og < 32) ? bq[og]
                       : (og < 64) ? bk[og - 32] * LOG2E
                                   : bv[og - 64];
#pragma unroll
            for (int mi = 0; mi < 2; mi++) {
                int n = n0 + mi * 16 + l15;
                unsigned short v16 = f2bf(acc[gi][mi][r] + bias);
                if (og < 32) {
                    qT[((size_t)b * NN + n) * C8 + og] = v16;
                } else {
                    proj[((size_t)b * PROJ_ROWS + og) * NN + n] = v16;
                }
            }
        }
    }
}

// ---------------------------------------------------------------------------
// Flash attention over the query axis (softmax over n, shift-invariant so no
// max subtraction; k pre-scaled by log2e -> raw v_exp_f32). R7 skeleton:
// 4 waves, block = 128c (ch half) x 64m, ps double-buffered, ONE barrier/iter,
// av/q register-prefetched one full iteration ahead of the barrier that
// drains them. R8: native exp2 + packed bf16 cvt + vector running sums.
// ---------------------------------------------------------------------------
template<int NSPLIT, bool FINAL>
__global__ __launch_bounds__(256, 4) void attn_kernel(
    const unsigned short* __restrict__ proj,
    const unsigned short* __restrict__ qT,
    const float* __restrict__ x,
    const float* __restrict__ gamma_p,
    float* __restrict__ out,
    unsigned short* __restrict__ Opart,
    float* __restrict__ Lpart)
{
    constexpr int ITERS = 64 / NSPLIT;
    int bid = blockIdx.x;
    int low = bid & 255;
    int xcd = low & 7;
    int b = xcd >> 1;
    int mtile = ((low >> 3) << 1) | (xcd & 1);
    int m0 = mtile * 64;
    int ch = (bid >> 8) & 1;
    int h  = bid >> 9;
    int nbase = h * (ITERS * 64);

    int tid = threadIdx.x;
    int w = tid >> 6, l = tid & 63, l15 = l & 15, lq = l >> 4;
    int cw = ch * 128 + w * 32;   // this wave's c base (32 c rows)

    __shared__ alignas(16) unsigned short ps[2][64][72];  // [buf][m][n]
    __shared__ float red[4][64];
    __shared__ float Ltot[64];

    const unsigned short* kbase = proj + ((size_t)b * PROJ_ROWS + C8) * NN;
    const unsigned short* vbase = proj + ((size_t)b * PROJ_ROWS + 64) * NN;
    const unsigned short* qbase = qT + (size_t)b * NN * C8;

    // k B-operand fragments: lane = k[c8=lq*8+j][m = m0+mi*16+l15]
    short8 kfrag[4];
#pragma unroll
    for (int mi = 0; mi < 4; mi++) {
        int col = m0 + mi * 16 + l15;
        unsigned short t8[8] __attribute__((aligned(16)));
#pragma unroll
        for (int j = 0; j < 8; j++)
            t8[j] = kbase[(size_t)(lq * 8 + j) * NN + col];
        kfrag[mi] = *(const short8*)t8;
    }

    f32x4 O[2][4];
#pragma unroll
    for (int ci = 0; ci < 2; ci++)
#pragma unroll
        for (int mi = 0; mi < 4; mi++) O[ci][mi] = (f32x4){0.f, 0.f, 0.f, 0.f};
    f32x4 runS[4];
#pragma unroll
    for (int mi = 0; mi < 4; mi++) runS[mi] = (f32x4){0.f, 0.f, 0.f, 0.f};

    // prologue: prefetch av for iter 0; S_0 -> exp2 -> ps[0]
    short8 avc[2][2];
#pragma unroll
    for (int kh = 0; kh < 2; kh++)
#pragma unroll
        for (int ci = 0; ci < 2; ci++)
            avc[kh][ci] = *(const short8*)(vbase
                + (size_t)(cw + ci * 16 + l15) * NN + nbase + kh * 32 + lq * 8);
    {
        short8 qf = *(const short8*)(qbase + (size_t)(nbase + 16 * w + l15) * C8 + lq * 8);
#pragma unroll
        for (int mi = 0; mi < 4; mi++) {
            f32x4 S = __builtin_amdgcn_mfma_f32_16x16x32_bf16(
                qf, kfrag[mi], (f32x4){0.f, 0.f, 0.f, 0.f}, 0, 0, 0);
            f32x4 P;
#pragma unroll
            for (int j = 0; j < 4; j++) P[j] = __builtin_amdgcn_exp2f(S[j]);
            runS[mi] += P;
            *(uint2*)&ps[0][mi * 16 + l15][16 * w + lq * 4]
                = make_uint2(pk2bf(P[0], P[1]), pk2bf(P[2], P[3]));
        }
    }

    for (int it = 0; it < ITERS; it++) {
        int n0c = nbase + it * 64;
        __syncthreads();  // ps[it&1] visible; WAR on ps[(it+1)&1] cleared

        // prefetch operands for it+1 NOW (drained by the NEXT barrier, a
        // full iteration away -> latency hidden)
        short8 avn[2][2];
        short8 qn;
        if (it + 1 < ITERS) {
            int nn = n0c + 64;
#pragma unroll
            for (int kh = 0; kh < 2; kh++)
#pragma unroll
                for (int ci = 0; ci < 2; ci++)
                    avn[kh][ci] = *(const short8*)(vbase
                        + (size_t)(cw + ci * 16 + l15) * NN + nn + kh * 32 + lq * 8);
            qn = *(const short8*)(qbase + (size_t)(nn + 16 * w + l15) * C8 + lq * 8);
        }

        // PV: O[c,m] += V[c,n] . P[n,m]
        const unsigned short* psrc = &ps[it & 1][0][0];
#pragma unroll
        for (int kh = 0; kh < 2; kh++) {
            short8 bfr[4];
#pragma unroll
            for (int mi = 0; mi < 4; mi++)
                bfr[mi] = *(const short8*)(psrc + (mi * 16 + l15) * 72 + kh * 32 + lq * 8);
#pragma unroll
            for (int ci = 0; ci < 2; ci++)
#pragma unroll
                for (int mi = 0; mi < 4; mi++)
                    O[ci][mi] = __builtin_amdgcn_mfma_f32_16x16x32_bf16(
                        avc[kh][ci], bfr[mi], O[ci][mi], 0, 0, 0);
        }

        // S_{it+1} -> exp2 -> write ps[(it+1)&1]
        if (it + 1 < ITERS) {
#pragma unroll
            for (int mi = 0; mi < 4; mi++) {
                f32x4 S = __builtin_amdgcn_mfma_f32_16x16x32_bf16(
                    qn, kfrag[mi], (f32x4){0.f, 0.f, 0.f, 0.f}, 0, 0, 0);
                f32x4 P;
#pragma unroll
                for (int j = 0; j < 4; j++) P[j] = __builtin_amdgcn_exp2f(S[j]);
                runS[mi] += P;
                *(uint2*)(&ps[(it + 1) & 1][0][0] + (mi * 16 + l15) * 72 + 16 * w + lq * 4)
                    = make_uint2(pk2bf(P[0], P[1]), pk2bf(P[2], P[3]));
            }
#pragma unroll
            for (int kh = 0; kh < 2; kh++)
#pragma unroll
                for (int ci = 0; ci < 2; ci++) avc[kh][ci] = avn[kh][ci];
        }
    }

    // column sums: in-lane, cross-lane (row quads), then cross-wave via LDS
#pragma unroll
    for (int mi = 0; mi < 4; mi++) {
        float s = (runS[mi][0] + runS[mi][1]) + (runS[mi][2] + runS[mi][3]);
        s += __shfl_xor(s, 16);
        s += __shfl_xor(s, 32);
        red[w][mi * 16 + l15] = s;
    }
    __syncthreads();
    if (tid < 64) Ltot[tid] = red[0][tid] + red[1][tid] + red[2][tid] + red[3][tid];
    __syncthreads();

    if constexpr (FINAL) {
        float gamma = gamma_p[0];
        float iv[4];
#pragma unroll
        for (int mi = 0; mi < 4; mi++) iv[mi] = 1.0f / Ltot[mi * 16 + l15];
#pragma unroll
        for (int ci = 0; ci < 2; ci++) {
#pragma unroll
            for (int mi = 0; mi < 4; mi++) {
                int m = m0 + mi * 16 + l15;
#pragma unroll
                for (int r = 0; r < 4; r++) {
                    int c = cw + ci * 16 + lq * 4 + r;
                    size_t idx = ((size_t)b * CC + c) * NN + m;
                    out[idx] = gamma * (O[ci][mi][r] * iv[mi]) + x[idx];
                }
            }
        }
    } else {
        size_t p = ((size_t)h * BN + b) * 64 + mtile;
        if (ch == 0 && tid < 64) Lpart[p * 64 + tid] = Ltot[tid];
        // Opart layout [p][m 64][c 256] bf16; r is c-contiguous -> uint2 stores
        unsigned short* Ob = Opart + p * (size_t)(64 * 256);
#pragma unroll
        for (int ci = 0; ci < 2; ci++) {
#pragma unroll
            for (int mi = 0; mi < 4; mi++) {
                *(uint2*)(Ob + (size_t)(mi * 16 + l15) * 256 + cw + ci * 16 + lq * 4)
                    = make_uint2(pk2bf(O[ci][mi][0], O[ci][mi][1]),
                                 pk2bf(O[ci][mi][2], O[ci][mi][3]));
            }
        }
    }
}

// ---------------------------------------------------------------------------
// Combine: out = gamma * (sum_h O_h) / (sum_h L_h) + x. Opart bf16 [m][c].
// Grid 1024 = (b, mt, c-quarter); LDS transpose for coalesced out writes.
// ---------------------------------------------------------------------------
template<int NSPLIT>
__global__ __launch_bounds__(256) void combine_kernel(
    const unsigned short* __restrict__ Opart, const float* __restrict__ Lpart,
    const float* __restrict__ x, const float* __restrict__ gamma_p,
    float* __restrict__ out)
{
    int bid = blockIdx.x;
    int cq = bid & 3;
    int mt = (bid >> 2) & 63;
    int b  = bid >> 8;
    int tid = threadIdx.x;
    float gamma = gamma_p[0];

    __shared__ float trans[64][65];   // [c_local][m]

    int m  = tid >> 2;                // phase A: one m per thread
    int cg = (tid & 3) * 16;          // 16-c group within the quarter

    float Ls = 0.f;
#pragma unroll
    for (int hh = 0; hh < NSPLIT; hh++)
        Ls += Lpart[(((size_t)hh * BN + b) * 64 + mt) * 64 + m];
    float scale = gamma / Ls;

    float acc[16];
#pragma unroll
    for (int j = 0; j < 16; j++) acc[j] = 0.f;
#pragma unroll
    for (int hh = 0; hh < NSPLIT; hh++) {
        const unsigned short* row = Opart
            + (((size_t)hh * BN + b) * 64 + mt) * (size_t)(64 * 256)
            + (size_t)m * 256 + cq * 64 + cg;
#pragma unroll
        for (int j4 = 0; j4 < 4; j4++) {
            uint2 u = *(const uint2*)(row + j4 * 4);
            acc[j4 * 4 + 0] += bflo2f(u.x);
            acc[j4 * 4 + 1] += bfhi2f(u.x);
            acc[j4 * 4 + 2] += bflo2f(u.y);
            acc[j4 * 4 + 3] += bfhi2f(u.y);
        }
    }
#pragma unroll
    for (int j = 0; j < 16; j++) trans[cg + j][m] = acc[j] * scale;
    __syncthreads();

    // phase B: c_local = tid>>2, 16 m per thread, coalesced float4 out
    int c  = tid >> 2;
    int mg = (tid & 3) * 16;
    size_t idx = ((size_t)b * CC + cq * 64 + c) * NN + mt * 64 + mg;
#pragma unroll
    for (int j4 = 0; j4 < 4; j4++) {
        f32x4 xv = *(const f32x4*)(x + idx + j4 * 4);
        f32x4 o;
#pragma unroll
        for (int j = 0; j < 4; j++) o[j] = trans[c][mg + j4 * 4 + j] + xv[j];
        *(f32x4*)(out + idx + j4 * 4) = o;
    }
}

extern "C" void kernel_launch(void* const* d_in, const int* in_sizes, int n_in,
                              void* d_out, int out_size, void* d_ws, size_t ws_size,
                              hipStream_t stream) {
    const float* x     = (const float*)d_in[0];
    const float* Wq    = (const float*)d_in[1];
    const float* bq    = (const float*)d_in[2];
    const float* Wk    = (const float*)d_in[3];
    const float* bk    = (const float*)d_in[4];
    const float* Wv    = (const float*)d_in[5];
    const float* bv    = (const float*)d_in[6];
    const float* gamma = (const float*)d_in[7];
    float* out = (float*)d_out;
    (void)in_sizes; (void)n_in; (void)out_size;

    unsigned short* proj = (unsigned short*)d_ws;
    unsigned short* qT   = proj + (size_t)BN * PROJ_ROWS * NN;
    unsigned short* Wbf  = qT + (size_t)BN * NN * C8;
    const size_t baseB = ((size_t)BN * PROJ_ROWS * NN
                        + (size_t)BN * NN * C8
                        + (size_t)PROJ_ROWS * CC) * 2;

    auto needB = [&](size_t ns) {
        size_t LpB = ns * BN * 64 * 64 * 4;                  // fp32 L partials
        size_t OpB = ns * BN * 64 * (size_t)(64 * 256) * 2;  // bf16 O partials
        return baseB + LpB + OpB;
    };

    wcast_kernel<<<320, 256, 0, stream>>>(Wq, Wk, Wv, Wbf);
    proj_kernel<<<512, 256, 0, stream>>>(x, Wbf, bq, bk, bv, proj, qT);

    if (ws_size >= needB(4)) {
        float* Lpart = (float*)((char*)d_ws + baseB);
        unsigned short* Opart = (unsigned short*)(Lpart + (size_t)4 * BN * 64 * 64);
        attn_kernel<4, false><<<2048, 256, 0, stream>>>(proj, qT, x, gamma, out, Opart, Lpart);
        combine_kernel<4><<<1024, 256, 0, stream>>>(Opart, Lpart, x, gamma, out);
    } else if (ws_size >= needB(2)) {
        float* Lpart = (float*)((char*)d_ws + baseB);
        unsigned short* Opart = (unsigned short*)(Lpart + (size_t)2 * BN * 64 * 64);
        attn_kernel<2, false><<<1024, 256, 0, stream>>>(proj, qT, x, gamma, out, Opart, Lpart);
        combine_kernel<2><<<1024, 256, 0, stream>>>(Opart, Lpart, x, gamma, out);
    } else {
        attn_kernel<1, true><<<512, 256, 0, stream>>>(proj, qT, x, gamma, out, nullptr, nullptr);
    }
}